// Round 1
// baseline (1396.649 us; speedup 1.0000x reference)
//
#include <hip/hip_runtime.h>
#include <cstdint>

#define B_ 4
#define T_ 2048
#define D_ 1024
#define E_ 8
#define F_ 4096
#define K_ 2
#define N_ (B_*T_)      // 8192 tokens
#define NR_ (N_*K_)     // 16384 routed slots

#define TM 128
#define TN 128
#define BK 32

typedef __attribute__((ext_vector_type(8))) short short8;
typedef __attribute__((ext_vector_type(4))) float f32x4;

typedef const __attribute__((address_space(1))) unsigned int* gp1_t;
typedef __attribute__((address_space(3))) unsigned int* lp3_t;

__device__ __forceinline__ void gl_lds16(const void* g, void* l) {
    __builtin_amdgcn_global_load_lds((gp1_t)g, (lp3_t)l, 16, 0, 0);
}

__device__ __forceinline__ unsigned short f2b(float f) {
    union { float f; unsigned int u; } v; v.f = f;
    unsigned int u = v.u;
    return (unsigned short)((u + 0x7FFFu + ((u >> 16) & 1u)) >> 16);
}

__device__ __forceinline__ float gelu_exact(float x) {
    return 0.5f * x * (1.0f + erff(x * 0.70710678118654752440f));
}

// ---------------- gate: fp32 logits, top-2, softmax ----------------
// one wave per token; lane: e = lane&7, chunk c = lane>>3 (128 d-elems each)
__global__ __launch_bounds__(256) void gate_kernel(
    const float* __restrict__ x, const float* __restrict__ Wg,
    const float* __restrict__ bg, int* __restrict__ topi,
    float* __restrict__ topw, int* __restrict__ counts) {
    int tid  = threadIdx.x;
    int lane = tid & 63;
    int tok  = blockIdx.x * 4 + (tid >> 6);
    int e = lane & 7;
    int c = lane >> 3;
    const float4* xp = (const float4*)(x + (size_t)tok * D_ + c * 128);
    const float*  wp = Wg + (size_t)(c * 128) * E_ + e;
    float acc = 0.f;
    #pragma unroll 8
    for (int i = 0; i < 32; ++i) {
        float4 xv = xp[i];
        acc += xv.x * wp[(i*4+0)*E_];
        acc += xv.y * wp[(i*4+1)*E_];
        acc += xv.z * wp[(i*4+2)*E_];
        acc += xv.w * wp[(i*4+3)*E_];
    }
    acc += __shfl_xor(acc, 8, 64);
    acc += __shfl_xor(acc, 16, 64);
    acc += __shfl_xor(acc, 32, 64);
    float logit = acc + bg[e];
    // top-2, stable (lower index wins ties) to match lax.top_k
    float v1 = -3.4e38f, v2 = -3.4e38f; int i1 = -1, i2 = -1;
    for (int ee = 0; ee < 8; ++ee) {
        float le = __shfl(logit, ee, 64);
        if (le > v1) { v2 = v1; i2 = i1; v1 = le; i1 = ee; }
        else if (le > v2) { v2 = le; i2 = ee; }
    }
    if (lane == 0) {
        float p2 = expf(v2 - v1);
        float s  = 1.0f + p2;
        topi[tok*2]   = i1; topw[tok*2]   = 1.0f / s;
        topi[tok*2+1] = i2; topw[tok*2+1] = p2 / s;
        atomicAdd(&counts[i1], 1);
        atomicAdd(&counts[i2], 1);
    }
}

__global__ void scan_kernel(const int* __restrict__ counts,
                            int* __restrict__ offsets, int* __restrict__ cursors) {
    if (threadIdx.x == 0) {
        int s = 0;
        for (int e = 0; e < E_; ++e) { offsets[e] = s; cursors[e] = s; s += counts[e]; }
        offsets[E_] = s;
    }
}

__global__ __launch_bounds__(256) void scatter_kernel(
    const int* __restrict__ topi, const float* __restrict__ topw,
    int* __restrict__ cursors, int* __restrict__ perm, float* __restrict__ rw) {
    int t = blockIdx.x * blockDim.x + threadIdx.x;
    if (t >= N_) return;
    #pragma unroll
    for (int k = 0; k < K_; ++k) {
        int e = topi[t*2 + k];
        int pos = atomicAdd(&cursors[e], 1);
        perm[pos] = t;
        rw[pos]   = topw[t*2 + k];
    }
}

// ---------------- casts ----------------
__global__ __launch_bounds__(256) void castx_kernel(
    const float* __restrict__ x, unsigned short* __restrict__ xb) {
    int i = blockIdx.x * blockDim.x + threadIdx.x;   // over N*D/4
    float4 v = ((const float4*)x)[i];
    ushort4 o; o.x = f2b(v.x); o.y = f2b(v.y); o.z = f2b(v.z); o.w = f2b(v.w);
    ((ushort4*)xb)[i] = o;
}

// batched fp32 [R,C] -> bf16 [C,R]
__global__ __launch_bounds__(256) void tcast_kernel(
    const float* __restrict__ src, unsigned short* __restrict__ dst, int R, int C) {
    __shared__ float tile[32][33];
    int rb = blockIdx.x * 32, cb = blockIdx.y * 32;
    const float* s = src + (size_t)blockIdx.z * R * C;
    unsigned short* d = dst + (size_t)blockIdx.z * R * C;
    int tx = threadIdx.x, ty = threadIdx.y;          // 32 x 8
    #pragma unroll
    for (int i = 0; i < 32; i += 8)
        tile[ty + i][tx] = s[(size_t)(rb + ty + i) * C + cb + tx];
    __syncthreads();
    #pragma unroll
    for (int i = 0; i < 32; i += 8)
        d[(size_t)(cb + ty + i) * R + rb + tx] = f2b(tile[tx][ty + i]);
}

// ---------------- GEMM1: H = gelu(Xb[perm] @ W1[e] + b1[e]) ----------------
// grid (64, F/TN, E); A gathered rows of Xb; B = W1t[e] ([F,D], K-minor)
__global__ __launch_bounds__(256, 2) void ffn1_kernel(
    const unsigned short* __restrict__ Xb, const unsigned short* __restrict__ W1t,
    const float* __restrict__ b1, const int* __restrict__ perm,
    const int* __restrict__ offsets, unsigned short* __restrict__ H) {
    int e = blockIdx.z;
    int seg_start = offsets[e], seg_end = offsets[e+1];
    int m0 = seg_start + blockIdx.x * TM;
    if (m0 >= seg_end) return;
    int n0 = blockIdx.y * TN;
    const unsigned short* Bw = W1t + (size_t)e * F_ * D_;

    __shared__ __align__(16) unsigned short lA[TM*BK];
    __shared__ __align__(16) unsigned short lB[TN*BK];

    int t = threadIdx.x;
    int lane = t & 63;
    int wv = t >> 6;
    int wrow = (wv >> 1) * 64, wcol = (wv & 1) * 64;
    int lr = lane & 15, q = lane >> 4;

    int ar0 = t >> 2;          // staging row 0..63 per pass
    int ac  = (t & 3) * 8;     // k-col offset (ushorts) -> 16B chunk
    int tok0 = perm[min(m0 + ar0,      NR_-1)];
    int tok1 = perm[min(m0 + 64 + ar0, NR_-1)];

    f32x4 acc[4][4];
    #pragma unroll
    for (int mi = 0; mi < 4; ++mi)
        #pragma unroll
        for (int ni = 0; ni < 4; ++ni)
            acc[mi][ni] = (f32x4){0.f, 0.f, 0.f, 0.f};

    for (int kk = 0; kk < D_/BK; ++kk) {
        int k0 = kk * BK;
        gl_lds16(Xb + (size_t)tok0 * D_ + k0 + ac, &lA[t*8]);
        gl_lds16(Xb + (size_t)tok1 * D_ + k0 + ac, &lA[2048 + t*8]);
        gl_lds16(Bw + (size_t)(n0 + ar0)      * D_ + k0 + ac, &lB[t*8]);
        gl_lds16(Bw + (size_t)(n0 + 64 + ar0) * D_ + k0 + ac, &lB[2048 + t*8]);
        asm volatile("s_waitcnt vmcnt(0)" ::: "memory");
        __syncthreads();
        short8 af[4], bf[4];
        #pragma unroll
        for (int mi = 0; mi < 4; ++mi)
            af[mi] = *(const short8*)&lA[(wrow + mi*16 + lr)*BK + q*8];
        #pragma unroll
        for (int ni = 0; ni < 4; ++ni)
            bf[ni] = *(const short8*)&lB[(wcol + ni*16 + lr)*BK + q*8];
        #pragma unroll
        for (int mi = 0; mi < 4; ++mi)
            #pragma unroll
            for (int ni = 0; ni < 4; ++ni)
                acc[mi][ni] = __builtin_amdgcn_mfma_f32_16x16x32_bf16(
                    af[mi], bf[ni], acc[mi][ni], 0, 0, 0);
        __syncthreads();
    }

    const float* b1e = b1 + (size_t)e * F_;
    #pragma unroll
    for (int mi = 0; mi < 4; ++mi) {
        int gr = m0 + wrow + mi*16 + q*4;
        #pragma unroll
        for (int ni = 0; ni < 4; ++ni) {
            int f = n0 + wcol + ni*16 + lr;
            float bb = b1e[f];
            #pragma unroll
            for (int r = 0; r < 4; ++r) {
                int row = gr + r;
                if (row < seg_end) {
                    float h = gelu_exact(acc[mi][ni][r] + bb);
                    H[(size_t)row * F_ + f] = f2b(h);
                }
            }
        }
    }
}

// ---------------- GEMM2: out[perm[p]] += rw[p] * (H[p] @ W2[e] + b2[e]) ----
// grid (64, D/TN, E); A = H rows (dense), B = W2t[e] ([D,F], K-minor)
__global__ __launch_bounds__(256, 2) void ffn2_kernel(
    const unsigned short* __restrict__ H, const unsigned short* __restrict__ W2t,
    const float* __restrict__ b2, const int* __restrict__ perm,
    const float* __restrict__ rw, const int* __restrict__ offsets,
    float* __restrict__ out) {
    int e = blockIdx.z;
    int seg_start = offsets[e], seg_end = offsets[e+1];
    int m0 = seg_start + blockIdx.x * TM;
    if (m0 >= seg_end) return;
    int n0 = blockIdx.y * TN;
    const unsigned short* Bw = W2t + (size_t)e * D_ * F_;

    __shared__ __align__(16) unsigned short lA[TM*BK];
    __shared__ __align__(16) unsigned short lB[TN*BK];

    int t = threadIdx.x;
    int lane = t & 63;
    int wv = t >> 6;
    int wrow = (wv >> 1) * 64, wcol = (wv & 1) * 64;
    int lr = lane & 15, q = lane >> 4;

    int ar0 = t >> 2;
    int ac  = (t & 3) * 8;
    size_t hr0 = (size_t)min(m0 + ar0,      NR_-1) * F_;
    size_t hr1 = (size_t)min(m0 + 64 + ar0, NR_-1) * F_;

    f32x4 acc[4][4];
    #pragma unroll
    for (int mi = 0; mi < 4; ++mi)
        #pragma unroll
        for (int ni = 0; ni < 4; ++ni)
            acc[mi][ni] = (f32x4){0.f, 0.f, 0.f, 0.f};

    for (int kk = 0; kk < F_/BK; ++kk) {
        int k0 = kk * BK;
        gl_lds16(H + hr0 + k0 + ac, &lA[t*8]);
        gl_lds16(H + hr1 + k0 + ac, &lA[2048 + t*8]);
        gl_lds16(Bw + (size_t)(n0 + ar0)      * F_ + k0 + ac, &lB[t*8]);
        gl_lds16(Bw + (size_t)(n0 + 64 + ar0) * F_ + k0 + ac, &lB[2048 + t*8]);
        asm volatile("s_waitcnt vmcnt(0)" ::: "memory");
        __syncthreads();
        short8 af[4], bf[4];
        #pragma unroll
        for (int mi = 0; mi < 4; ++mi)
            af[mi] = *(const short8*)&lA[(wrow + mi*16 + lr)*BK + q*8];
        #pragma unroll
        for (int ni = 0; ni < 4; ++ni)
            bf[ni] = *(const short8*)&lB[(wcol + ni*16 + lr)*BK + q*8];
        #pragma unroll
        for (int mi = 0; mi < 4; ++mi)
            #pragma unroll
            for (int ni = 0; ni < 4; ++ni)
                acc[mi][ni] = __builtin_amdgcn_mfma_f32_16x16x32_bf16(
                    af[mi], bf[ni], acc[mi][ni], 0, 0, 0);
        __syncthreads();
    }

    const float* b2e = b2 + (size_t)e * D_;
    #pragma unroll
    for (int mi = 0; mi < 4; ++mi) {
        int gr = m0 + wrow + mi*16 + q*4;
        #pragma unroll
        for (int r = 0; r < 4; ++r) {
            int row = gr + r;
            if (row < seg_end) {
                int tok = perm[row];
                float w = rw[row];
                #pragma unroll
                for (int ni = 0; ni < 4; ++ni) {
                    int dcol = n0 + wcol + ni*16 + lr;
                    atomicAdd(&out[(size_t)tok * D_ + dcol],
                              w * (acc[mi][ni][r] + b2e[dcol]));
                }
            }
        }
    }
}

extern "C" void kernel_launch(void* const* d_in, const int* in_sizes, int n_in,
                              void* d_out, int out_size, void* d_ws, size_t ws_size,
                              hipStream_t stream) {
    const float* x  = (const float*)d_in[0];
    const float* Wg = (const float*)d_in[1];
    const float* bg = (const float*)d_in[2];
    const float* W1 = (const float*)d_in[3];
    const float* b1 = (const float*)d_in[4];
    const float* W2 = (const float*)d_in[5];
    const float* b2 = (const float*)d_in[6];
    float* out = (float*)d_out;

    char* wsp = (char*)d_ws;
    size_t off = 0;
    auto alloc = [&](size_t bytes) {
        void* p = wsp + off;
        off += (bytes + 255) & ~(size_t)255;
        return p;
    };
    int*   topi    = (int*)  alloc((size_t)NR_*4);
    float* topw    = (float*)alloc((size_t)NR_*4);
    int*   counts  = (int*)  alloc(E_*4);
    int*   offsets = (int*)  alloc((E_+1)*4);
    int*   cursors = (int*)  alloc(E_*4);
    int*   perm    = (int*)  alloc((size_t)NR_*4);
    float* rwa     = (float*)alloc((size_t)NR_*4);
    unsigned short* Xb  = (unsigned short*)alloc((size_t)N_*D_*2);
    unsigned short* W1t = (unsigned short*)alloc((size_t)E_*D_*F_*2);
    unsigned short* W2t = (unsigned short*)alloc((size_t)E_*D_*F_*2);
    unsigned short* Hb  = (unsigned short*)alloc((size_t)NR_*F_*2);

    hipMemsetAsync(d_out, 0, (size_t)N_*D_*4, stream);
    hipMemsetAsync(counts, 0, E_*4, stream);

    gate_kernel<<<N_/4, 256, 0, stream>>>(x, Wg, bg, topi, topw, counts);
    scan_kernel<<<1, 64, 0, stream>>>(counts, offsets, cursors);
    scatter_kernel<<<N_/256, 256, 0, stream>>>(topi, topw, cursors, perm, rwa);
    castx_kernel<<<(N_*(size_t)D_/4)/256, 256, 0, stream>>>(x, Xb);
    dim3 tb(32, 8);
    tcast_kernel<<<dim3(D_/32, F_/32, E_), tb, 0, stream>>>(W1, W1t, D_, F_);
    tcast_kernel<<<dim3(F_/32, D_/32, E_), tb, 0, stream>>>(W2, W2t, F_, D_);
    ffn1_kernel<<<dim3(64, F_/TN, E_), 256, 0, stream>>>(Xb, W1t, b1, perm, offsets, Hb);
    ffn2_kernel<<<dim3(64, D_/TN, E_), 256, 0, stream>>>(Hb, W2t, b2, perm, rwa, offsets, out);
}

// Round 2
// 1143.834 us; speedup vs baseline: 1.2210x; 1.2210x over previous
//
#include <hip/hip_runtime.h>
#include <cstdint>

#define B_ 4
#define T_ 2048
#define D_ 1024
#define E_ 8
#define F_ 4096
#define K_ 2
#define N_ (B_*T_)      // 8192 tokens
#define NR_ (N_*K_)     // 16384 routed slots

#define TM 128
#define TN 128
#define BK 32
#define MAXP (NR_ + E_*TM)       // padded slot capacity (17408)
#define MAXMB (NR_/TM + E_)      // max M-blocks (136)

typedef __attribute__((ext_vector_type(8))) short short8;
typedef __attribute__((ext_vector_type(4))) float f32x4;

typedef const __attribute__((address_space(1))) unsigned int* gp1_t;
typedef __attribute__((address_space(3))) unsigned int* lp3_t;

__device__ __forceinline__ void gl_lds16(const void* g, void* l) {
    __builtin_amdgcn_global_load_lds((gp1_t)g, (lp3_t)l, 16, 0, 0);
}

__device__ __forceinline__ unsigned short f2b(float f) {
    union { float f; unsigned int u; } v; v.f = f;
    unsigned int u = v.u;
    return (unsigned short)((u + 0x7FFFu + ((u >> 16) & 1u)) >> 16);
}

__device__ __forceinline__ float gelu_exact(float x) {
    return 0.5f * x * (1.0f + erff(x * 0.70710678118654752440f));
}

// ---------------- gate: fp32 logits, top-2, softmax ----------------
__global__ __launch_bounds__(256) void gate_kernel(
    const float* __restrict__ x, const float* __restrict__ Wg,
    const float* __restrict__ bg, int* __restrict__ topi,
    float* __restrict__ topw, int* __restrict__ counts) {
    int tid  = threadIdx.x;
    int lane = tid & 63;
    int tok  = blockIdx.x * 4 + (tid >> 6);
    int e = lane & 7;
    int c = lane >> 3;
    const float4* xp = (const float4*)(x + (size_t)tok * D_ + c * 128);
    const float*  wp = Wg + (size_t)(c * 128) * E_ + e;
    float acc = 0.f;
    #pragma unroll 8
    for (int i = 0; i < 32; ++i) {
        float4 xv = xp[i];
        acc += xv.x * wp[(i*4+0)*E_];
        acc += xv.y * wp[(i*4+1)*E_];
        acc += xv.z * wp[(i*4+2)*E_];
        acc += xv.w * wp[(i*4+3)*E_];
    }
    acc += __shfl_xor(acc, 8, 64);
    acc += __shfl_xor(acc, 16, 64);
    acc += __shfl_xor(acc, 32, 64);
    float logit = acc + bg[e];
    float v1 = -3.4e38f, v2 = -3.4e38f; int i1 = -1, i2 = -1;
    for (int ee = 0; ee < 8; ++ee) {
        float le = __shfl(logit, ee, 64);
        if (le > v1) { v2 = v1; i2 = i1; v1 = le; i1 = ee; }
        else if (le > v2) { v2 = le; i2 = ee; }
    }
    if (lane == 0) {
        float p2 = expf(v2 - v1);
        float s  = 1.0f + p2;
        topi[tok*2]   = i1; topw[tok*2]   = 1.0f / s;
        topi[tok*2+1] = i2; topw[tok*2+1] = p2 / s;
        atomicAdd(&counts[i1], 1);
        atomicAdd(&counts[i2], 1);
    }
}

// scan: padded offsets + flat M-block tables
__global__ void scan_kernel(const int* __restrict__ counts,
                            int* __restrict__ offs, int* __restrict__ cursors,
                            int* __restrict__ mb_e, int* __restrict__ mb_m0) {
    if (threadIdx.x == 0) {
        int s = 0, mb = 0;
        for (int e = 0; e < E_; ++e) {
            offs[e] = s; cursors[e] = s;
            int nb = (counts[e] + TM - 1) / TM;
            for (int i = 0; i < nb; ++i) { mb_e[mb] = e; mb_m0[mb] = s + i*TM; ++mb; }
            s += nb * TM;
        }
        offs[E_] = s;
        for (int b = mb; b < MAXMB; ++b) mb_e[b] = -1;
    }
}

__global__ __launch_bounds__(256) void scatter_kernel(
    const int* __restrict__ topi, int* __restrict__ cursors,
    int* __restrict__ perm, int* __restrict__ slots) {
    int t = blockIdx.x * blockDim.x + threadIdx.x;
    if (t >= N_) return;
    #pragma unroll
    for (int k = 0; k < K_; ++k) {
        int e = topi[t*2 + k];
        int pos = atomicAdd(&cursors[e], 1);
        perm[pos] = t;
        slots[t*2 + k] = pos;
    }
}

// ---------------- casts ----------------
__global__ __launch_bounds__(256) void castx_kernel(
    const float* __restrict__ x, unsigned short* __restrict__ xb) {
    int i = blockIdx.x * blockDim.x + threadIdx.x;   // over N*D/4
    float4 v = ((const float4*)x)[i];
    ushort4 o; o.x = f2b(v.x); o.y = f2b(v.y); o.z = f2b(v.z); o.w = f2b(v.w);
    ((ushort4*)xb)[i] = o;
}

// batched fp32 [R,C] -> bf16 [C,R]; 64x64 tile, vectorized
__global__ __launch_bounds__(256) void tcast_kernel(
    const float* __restrict__ src, unsigned short* __restrict__ dst, int R, int C) {
    __shared__ float tile[64][65];
    int rb = blockIdx.x * 64, cb = blockIdx.y * 64;
    const float* s = src + (size_t)blockIdx.z * R * C;
    unsigned short* d = dst + (size_t)blockIdx.z * R * C;
    int tx = threadIdx.x & 15, ty = threadIdx.x >> 4;   // 16 x 16
    #pragma unroll
    for (int i = 0; i < 4; ++i) {
        int r = ty + i*16;
        float4 v = *(const float4*)&s[(size_t)(rb + r) * C + cb + tx*4];
        tile[r][tx*4+0] = v.x; tile[r][tx*4+1] = v.y;
        tile[r][tx*4+2] = v.z; tile[r][tx*4+3] = v.w;
    }
    __syncthreads();
    #pragma unroll
    for (int i = 0; i < 4; ++i) {
        int c = ty + i*16;                               // dst row
        ushort4 o;
        o.x = f2b(tile[tx*4+0][c]);
        o.y = f2b(tile[tx*4+1][c]);
        o.z = f2b(tile[tx*4+2][c]);
        o.w = f2b(tile[tx*4+3][c]);
        *(ushort4*)&d[(size_t)(cb + c) * R + rb + tx*4] = o;
    }
}

// ---------------- GEMM1: H = gelu(Xb[perm] @ W1[e] + b1[e]) ----------------
// grid (MAXMB, F/TN); flat padded M-blocks
__global__ __launch_bounds__(256, 4) void ffn1_kernel(
    const unsigned short* __restrict__ Xb, const unsigned short* __restrict__ W1t,
    const float* __restrict__ b1, const int* __restrict__ perm,
    const int* __restrict__ mb_e, const int* __restrict__ mb_m0,
    unsigned short* __restrict__ H) {
    int e = mb_e[blockIdx.x];
    if (e < 0) return;
    int m0 = mb_m0[blockIdx.x];
    int n0 = blockIdx.y * TN;
    const unsigned short* Bw = W1t + (size_t)e * F_ * D_;

    __shared__ __align__(16) unsigned short lA[TM*BK];
    __shared__ __align__(16) unsigned short lB[TN*BK];

    int t = threadIdx.x;
    int lane = t & 63;
    int wv = t >> 6;
    int wrow = (wv >> 1) * 64, wcol = (wv & 1) * 64;
    int lr = lane & 15, q = lane >> 4;

    int ar0 = t >> 2;
    int ac  = (t & 3) * 8;
    int tok0 = perm[m0 + ar0];
    int tok1 = perm[m0 + 64 + ar0];
    const unsigned short* pa0 = Xb + (size_t)tok0 * D_ + ac;
    const unsigned short* pa1 = Xb + (size_t)tok1 * D_ + ac;
    const unsigned short* pb0 = Bw + (size_t)(n0 + ar0)      * D_ + ac;
    const unsigned short* pb1 = Bw + (size_t)(n0 + 64 + ar0) * D_ + ac;

    f32x4 acc[4][4];
    #pragma unroll
    for (int mi = 0; mi < 4; ++mi)
        #pragma unroll
        for (int ni = 0; ni < 4; ++ni)
            acc[mi][ni] = (f32x4){0.f, 0.f, 0.f, 0.f};

    for (int kk = 0; kk < D_/BK; ++kk) {
        int k0 = kk * BK;
        gl_lds16(pa0 + k0, &lA[t*8]);
        gl_lds16(pa1 + k0, &lA[2048 + t*8]);
        gl_lds16(pb0 + k0, &lB[t*8]);
        gl_lds16(pb1 + k0, &lB[2048 + t*8]);
        asm volatile("s_waitcnt vmcnt(0)" ::: "memory");
        __syncthreads();
        short8 af[4], bf[4];
        #pragma unroll
        for (int mi = 0; mi < 4; ++mi)
            af[mi] = *(const short8*)&lA[(wrow + mi*16 + lr)*BK + q*8];
        #pragma unroll
        for (int ni = 0; ni < 4; ++ni)
            bf[ni] = *(const short8*)&lB[(wcol + ni*16 + lr)*BK + q*8];
        #pragma unroll
        for (int mi = 0; mi < 4; ++mi)
            #pragma unroll
            for (int ni = 0; ni < 4; ++ni)
                acc[mi][ni] = __builtin_amdgcn_mfma_f32_16x16x32_bf16(
                    af[mi], bf[ni], acc[mi][ni], 0, 0, 0);
        __syncthreads();
    }

    const float* b1e = b1 + (size_t)e * F_;
    #pragma unroll
    for (int mi = 0; mi < 4; ++mi) {
        int gr = m0 + wrow + mi*16 + q*4;
        #pragma unroll
        for (int ni = 0; ni < 4; ++ni) {
            int f = n0 + wcol + ni*16 + lr;
            float bb = b1e[f];
            #pragma unroll
            for (int r = 0; r < 4; ++r) {
                float h = gelu_exact(acc[mi][ni][r] + bb);
                H[(size_t)(gr + r) * F_ + f] = f2b(h);
            }
        }
    }
}

// ---------------- GEMM2: Y[p] = H[p] @ W2[e] + b2[e] (fp32, plain stores) ---
// grid (MAXMB, D/TN)
__global__ __launch_bounds__(256, 4) void ffn2_kernel(
    const unsigned short* __restrict__ H, const unsigned short* __restrict__ W2t,
    const float* __restrict__ b2,
    const int* __restrict__ mb_e, const int* __restrict__ mb_m0,
    float* __restrict__ Y) {
    int e = mb_e[blockIdx.x];
    if (e < 0) return;
    int m0 = mb_m0[blockIdx.x];
    int n0 = blockIdx.y * TN;
    const unsigned short* Bw = W2t + (size_t)e * D_ * F_;

    __shared__ __align__(16) unsigned short lA[TM*BK];
    __shared__ __align__(16) unsigned short lB[TN*BK];

    int t = threadIdx.x;
    int lane = t & 63;
    int wv = t >> 6;
    int wrow = (wv >> 1) * 64, wcol = (wv & 1) * 64;
    int lr = lane & 15, q = lane >> 4;

    int ar0 = t >> 2;
    int ac  = (t & 3) * 8;
    const unsigned short* pa0 = H + (size_t)(m0 + ar0)      * F_ + ac;
    const unsigned short* pa1 = H + (size_t)(m0 + 64 + ar0) * F_ + ac;
    const unsigned short* pb0 = Bw + (size_t)(n0 + ar0)      * F_ + ac;
    const unsigned short* pb1 = Bw + (size_t)(n0 + 64 + ar0) * F_ + ac;

    f32x4 acc[4][4];
    #pragma unroll
    for (int mi = 0; mi < 4; ++mi)
        #pragma unroll
        for (int ni = 0; ni < 4; ++ni)
            acc[mi][ni] = (f32x4){0.f, 0.f, 0.f, 0.f};

    for (int kk = 0; kk < F_/BK; ++kk) {
        int k0 = kk * BK;
        gl_lds16(pa0 + k0, &lA[t*8]);
        gl_lds16(pa1 + k0, &lA[2048 + t*8]);
        gl_lds16(pb0 + k0, &lB[t*8]);
        gl_lds16(pb1 + k0, &lB[2048 + t*8]);
        asm volatile("s_waitcnt vmcnt(0)" ::: "memory");
        __syncthreads();
        short8 af[4], bf[4];
        #pragma unroll
        for (int mi = 0; mi < 4; ++mi)
            af[mi] = *(const short8*)&lA[(wrow + mi*16 + lr)*BK + q*8];
        #pragma unroll
        for (int ni = 0; ni < 4; ++ni)
            bf[ni] = *(const short8*)&lB[(wcol + ni*16 + lr)*BK + q*8];
        #pragma unroll
        for (int mi = 0; mi < 4; ++mi)
            #pragma unroll
            for (int ni = 0; ni < 4; ++ni)
                acc[mi][ni] = __builtin_amdgcn_mfma_f32_16x16x32_bf16(
                    af[mi], bf[ni], acc[mi][ni], 0, 0, 0);
        __syncthreads();
    }

    const float* b2e = b2 + (size_t)e * D_;
    #pragma unroll
    for (int mi = 0; mi < 4; ++mi) {
        int gr = m0 + wrow + mi*16 + q*4;
        #pragma unroll
        for (int ni = 0; ni < 4; ++ni) {
            int dcol = n0 + wcol + ni*16 + lr;
            float bb = b2e[dcol];
            #pragma unroll
            for (int r = 0; r < 4; ++r)
                Y[(size_t)(gr + r) * D_ + dcol] = acc[mi][ni][r] + bb;
        }
    }
}

// ---------------- combine: out[t] = w0*Y[s0] + w1*Y[s1] ----------------
__global__ __launch_bounds__(256) void combine_kernel(
    const float* __restrict__ Y, const int* __restrict__ slots,
    const float* __restrict__ topw, float* __restrict__ out) {
    int i = blockIdx.x * 256 + threadIdx.x;    // over N*D/4
    int t  = i >> 8;                           // D/4 = 256
    int d4 = (i & 255) * 4;
    int s0 = slots[t*2], s1 = slots[t*2+1];
    float w0 = topw[t*2], w1 = topw[t*2+1];
    float4 y0 = *(const float4*)&Y[(size_t)s0 * D_ + d4];
    float4 y1 = *(const float4*)&Y[(size_t)s1 * D_ + d4];
    float4 o;
    o.x = w0*y0.x + w1*y1.x;
    o.y = w0*y0.y + w1*y1.y;
    o.z = w0*y0.z + w1*y1.z;
    o.w = w0*y0.w + w1*y1.w;
    ((float4*)out)[i] = o;
}

extern "C" void kernel_launch(void* const* d_in, const int* in_sizes, int n_in,
                              void* d_out, int out_size, void* d_ws, size_t ws_size,
                              hipStream_t stream) {
    const float* x  = (const float*)d_in[0];
    const float* Wg = (const float*)d_in[1];
    const float* bg = (const float*)d_in[2];
    const float* W1 = (const float*)d_in[3];
    const float* b1 = (const float*)d_in[4];
    const float* W2 = (const float*)d_in[5];
    const float* b2 = (const float*)d_in[6];
    float* out = (float*)d_out;

    char* wsp = (char*)d_ws;
    size_t off = 0;
    auto alloc = [&](size_t bytes) {
        void* p = wsp + off;
        off += (bytes + 255) & ~(size_t)255;
        return p;
    };
    int*   topi    = (int*)  alloc((size_t)NR_*4);
    float* topw    = (float*)alloc((size_t)NR_*4);
    int*   slots   = (int*)  alloc((size_t)NR_*4);
    int*   counts  = (int*)  alloc(E_*4);
    int*   offs    = (int*)  alloc((E_+1)*4);
    int*   cursors = (int*)  alloc(E_*4);
    int*   mb_e    = (int*)  alloc(MAXMB*4);
    int*   mb_m0   = (int*)  alloc(MAXMB*4);
    int*   perm    = (int*)  alloc((size_t)MAXP*4);
    unsigned short* Xb  = (unsigned short*)alloc((size_t)N_*D_*2);
    unsigned short* W1t = (unsigned short*)alloc((size_t)E_*D_*F_*2);
    unsigned short* W2t = (unsigned short*)alloc((size_t)E_*D_*F_*2);
    unsigned short* Hb  = (unsigned short*)alloc((size_t)MAXP*F_*2);
    float*          Yb  = (float*)         alloc((size_t)MAXP*D_*4);

    hipMemsetAsync(counts, 0, E_*4, stream);
    hipMemsetAsync(perm, 0, (size_t)MAXP*4, stream);

    gate_kernel<<<N_/4, 256, 0, stream>>>(x, Wg, bg, topi, topw, counts);
    scan_kernel<<<1, 64, 0, stream>>>(counts, offs, cursors, mb_e, mb_m0);
    scatter_kernel<<<N_/256, 256, 0, stream>>>(topi, cursors, perm, slots);
    castx_kernel<<<(N_*(size_t)D_/4)/256, 256, 0, stream>>>(x, Xb);
    tcast_kernel<<<dim3(D_/64, F_/64, E_), 256, 0, stream>>>(W1, W1t, D_, F_);
    tcast_kernel<<<dim3(F_/64, D_/64, E_), 256, 0, stream>>>(W2, W2t, F_, D_);
    ffn1_kernel<<<dim3(MAXMB, F_/TN), 256, 0, stream>>>(Xb, W1t, b1, perm, mb_e, mb_m0, Hb);
    ffn2_kernel<<<dim3(MAXMB, D_/TN), 256, 0, stream>>>(Hb, W2t, b2, mb_e, mb_m0, Yb);
    combine_kernel<<<(N_*(size_t)D_/4)/256, 256, 0, stream>>>(Yb, slots, topw, out);
}

// Round 3
// 1136.205 us; speedup vs baseline: 1.2292x; 1.0067x over previous
//
#include <hip/hip_runtime.h>
#include <cstdint>

#define B_ 4
#define T_ 2048
#define D_ 1024
#define E_ 8
#define F_ 4096
#define K_ 2
#define N_ (B_*T_)      // 8192 tokens
#define NR_ (N_*K_)     // 16384 routed slots

#define TM 128
#define TN 256
#define BK 32
#define MAXP (NR_ + E_*TM)       // padded slot capacity (17408)
#define MAXMB (NR_/TM + E_)      // max M-blocks (136)

typedef __attribute__((ext_vector_type(8))) short short8;
typedef __attribute__((ext_vector_type(4))) float f32x4;

typedef const __attribute__((address_space(1))) unsigned int* gp1_t;
typedef __attribute__((address_space(3))) unsigned int* lp3_t;

__device__ __forceinline__ void gl_lds16(const void* g, void* l) {
    __builtin_amdgcn_global_load_lds((gp1_t)g, (lp3_t)l, 16, 0, 0);
}

__device__ __forceinline__ unsigned short f2b(float f) {
    union { float f; unsigned int u; } v; v.f = f;
    unsigned int u = v.u;
    return (unsigned short)((u + 0x7FFFu + ((u >> 16) & 1u)) >> 16);
}

__device__ __forceinline__ float b2f(unsigned short u) {
    union { unsigned int i; float f; } v; v.i = ((unsigned int)u) << 16;
    return v.f;
}

__device__ __forceinline__ float gelu_exact(float x) {
    return 0.5f * x * (1.0f + erff(x * 0.70710678118654752440f));
}

// ---------------- gate: fp32 logits, top-2, softmax ----------------
__global__ __launch_bounds__(256) void gate_kernel(
    const float* __restrict__ x, const float* __restrict__ Wg,
    const float* __restrict__ bg, int* __restrict__ topi,
    float* __restrict__ topw, int* __restrict__ counts) {
    int tid  = threadIdx.x;
    int lane = tid & 63;
    int tok  = blockIdx.x * 4 + (tid >> 6);
    int e = lane & 7;
    int c = lane >> 3;
    const float4* xp = (const float4*)(x + (size_t)tok * D_ + c * 128);
    const float*  wp = Wg + (size_t)(c * 128) * E_ + e;
    float acc = 0.f;
    #pragma unroll 8
    for (int i = 0; i < 32; ++i) {
        float4 xv = xp[i];
        acc += xv.x * wp[(i*4+0)*E_];
        acc += xv.y * wp[(i*4+1)*E_];
        acc += xv.z * wp[(i*4+2)*E_];
        acc += xv.w * wp[(i*4+3)*E_];
    }
    acc += __shfl_xor(acc, 8, 64);
    acc += __shfl_xor(acc, 16, 64);
    acc += __shfl_xor(acc, 32, 64);
    float logit = acc + bg[e];
    float v1 = -3.4e38f, v2 = -3.4e38f; int i1 = -1, i2 = -1;
    for (int ee = 0; ee < 8; ++ee) {
        float le = __shfl(logit, ee, 64);
        if (le > v1) { v2 = v1; i2 = i1; v1 = le; i1 = ee; }
        else if (le > v2) { v2 = le; i2 = ee; }
    }
    if (lane == 0) {
        float p2 = expf(v2 - v1);
        float s  = 1.0f + p2;
        topi[tok*2]   = i1; topw[tok*2]   = 1.0f / s;
        topi[tok*2+1] = i2; topw[tok*2+1] = p2 / s;
        atomicAdd(&counts[i1], 1);
        atomicAdd(&counts[i2], 1);
    }
}

// scan: padded offsets + flat M-block tables
__global__ void scan_kernel(const int* __restrict__ counts,
                            int* __restrict__ offs, int* __restrict__ cursors,
                            int* __restrict__ mb_e, int* __restrict__ mb_m0) {
    if (threadIdx.x == 0) {
        int s = 0, mb = 0;
        for (int e = 0; e < E_; ++e) {
            offs[e] = s; cursors[e] = s;
            int nb = (counts[e] + TM - 1) / TM;
            for (int i = 0; i < nb; ++i) { mb_e[mb] = e; mb_m0[mb] = s + i*TM; ++mb; }
            s += nb * TM;
        }
        offs[E_] = s;
        for (int b = mb; b < MAXMB; ++b) mb_e[b] = -1;
    }
}

__global__ __launch_bounds__(256) void scatter_kernel(
    const int* __restrict__ topi, int* __restrict__ cursors,
    int* __restrict__ perm, int* __restrict__ slots) {
    int t = blockIdx.x * blockDim.x + threadIdx.x;
    if (t >= N_) return;
    #pragma unroll
    for (int k = 0; k < K_; ++k) {
        int e = topi[t*2 + k];
        int pos = atomicAdd(&cursors[e], 1);
        perm[pos] = t;
        slots[t*2 + k] = pos;
    }
}

// ---------------- casts ----------------
__global__ __launch_bounds__(256) void castx_kernel(
    const float* __restrict__ x, unsigned short* __restrict__ xb) {
    int i = blockIdx.x * blockDim.x + threadIdx.x;   // over N*D/4
    float4 v = ((const float4*)x)[i];
    ushort4 o; o.x = f2b(v.x); o.y = f2b(v.y); o.z = f2b(v.z); o.w = f2b(v.w);
    ((ushort4*)xb)[i] = o;
}

// batched fp32 [R,C] -> bf16 [C,R]; 64x64 tile, vectorized
__global__ __launch_bounds__(256) void tcast_kernel(
    const float* __restrict__ src, unsigned short* __restrict__ dst, int R, int C) {
    __shared__ float tile[64][65];
    int rb = blockIdx.x * 64, cb = blockIdx.y * 64;
    const float* s = src + (size_t)blockIdx.z * R * C;
    unsigned short* d = dst + (size_t)blockIdx.z * R * C;
    int tx = threadIdx.x & 15, ty = threadIdx.x >> 4;   // 16 x 16
    #pragma unroll
    for (int i = 0; i < 4; ++i) {
        int r = ty + i*16;
        float4 v = *(const float4*)&s[(size_t)(rb + r) * C + cb + tx*4];
        tile[r][tx*4+0] = v.x; tile[r][tx*4+1] = v.y;
        tile[r][tx*4+2] = v.z; tile[r][tx*4+3] = v.w;
    }
    __syncthreads();
    #pragma unroll
    for (int i = 0; i < 4; ++i) {
        int c = ty + i*16;                               // dst row
        ushort4 o;
        o.x = f2b(tile[tx*4+0][c]);
        o.y = f2b(tile[tx*4+1][c]);
        o.z = f2b(tile[tx*4+2][c]);
        o.w = f2b(tile[tx*4+3][c]);
        *(ushort4*)&d[(size_t)(cb + c) * R + rb + tx*4] = o;
    }
}

// ---------------- GEMM1: H = gelu(Xb[perm] @ W1[e] + b1[e]) ----------------
// 128x256 tile; grid (MAXMB, F/TN); wave tile 64x128, acc 4x8
__global__ __launch_bounds__(256, 2) void ffn1_kernel(
    const unsigned short* __restrict__ Xb, const unsigned short* __restrict__ W1t,
    const float* __restrict__ b1, const int* __restrict__ perm,
    const int* __restrict__ mb_e, const int* __restrict__ mb_m0,
    unsigned short* __restrict__ H) {
    int e = mb_e[blockIdx.x];
    if (e < 0) return;
    int m0 = mb_m0[blockIdx.x];
    int n0 = blockIdx.y * TN;
    const unsigned short* Bw = W1t + (size_t)e * F_ * D_;

    __shared__ __align__(16) unsigned short lA[TM*BK];
    __shared__ __align__(16) unsigned short lB[TN*BK];

    int t = threadIdx.x;
    int lane = t & 63;
    int wv = t >> 6;
    int wrow = (wv >> 1) * 64, wcol = (wv & 1) * 128;
    int lr = lane & 15, q = lane >> 4;

    int ar0 = t >> 2;
    int ac  = (t & 3) * 8;
    int tok0 = perm[m0 + ar0];
    int tok1 = perm[m0 + 64 + ar0];
    const unsigned short* pa0 = Xb + (size_t)tok0 * D_ + ac;
    const unsigned short* pa1 = Xb + (size_t)tok1 * D_ + ac;
    const unsigned short* pb0 = Bw + (size_t)(n0 + ar0)       * D_ + ac;
    const unsigned short* pb1 = Bw + (size_t)(n0 + 64  + ar0) * D_ + ac;
    const unsigned short* pb2 = Bw + (size_t)(n0 + 128 + ar0) * D_ + ac;
    const unsigned short* pb3 = Bw + (size_t)(n0 + 192 + ar0) * D_ + ac;

    f32x4 acc[4][8];
    #pragma unroll
    for (int mi = 0; mi < 4; ++mi)
        #pragma unroll
        for (int ni = 0; ni < 8; ++ni)
            acc[mi][ni] = (f32x4){0.f, 0.f, 0.f, 0.f};

    for (int kk = 0; kk < D_/BK; ++kk) {
        int k0 = kk * BK;
        gl_lds16(pa0 + k0, &lA[t*8]);
        gl_lds16(pa1 + k0, &lA[2048 + t*8]);
        gl_lds16(pb0 + k0, &lB[t*8]);
        gl_lds16(pb1 + k0, &lB[2048 + t*8]);
        gl_lds16(pb2 + k0, &lB[4096 + t*8]);
        gl_lds16(pb3 + k0, &lB[6144 + t*8]);
        asm volatile("s_waitcnt vmcnt(0)" ::: "memory");
        __syncthreads();
        short8 af[4], bf[8];
        #pragma unroll
        for (int mi = 0; mi < 4; ++mi)
            af[mi] = *(const short8*)&lA[(wrow + mi*16 + lr)*BK + q*8];
        #pragma unroll
        for (int ni = 0; ni < 8; ++ni)
            bf[ni] = *(const short8*)&lB[(wcol + ni*16 + lr)*BK + q*8];
        #pragma unroll
        for (int mi = 0; mi < 4; ++mi)
            #pragma unroll
            for (int ni = 0; ni < 8; ++ni)
                acc[mi][ni] = __builtin_amdgcn_mfma_f32_16x16x32_bf16(
                    af[mi], bf[ni], acc[mi][ni], 0, 0, 0);
        __syncthreads();
    }

    const float* b1e = b1 + (size_t)e * F_;
    #pragma unroll
    for (int mi = 0; mi < 4; ++mi) {
        int gr = m0 + wrow + mi*16 + q*4;
        #pragma unroll
        for (int ni = 0; ni < 8; ++ni) {
            int f = n0 + wcol + ni*16 + lr;
            float bb = b1e[f];
            #pragma unroll
            for (int r = 0; r < 4; ++r) {
                float h = gelu_exact(acc[mi][ni][r] + bb);
                H[(size_t)(gr + r) * F_ + f] = f2b(h);
            }
        }
    }
}

// ---------------- GEMM2: Y[p] = H[p] @ W2[e] + b2[e] (bf16 stores) ---------
// 128x256 tile; grid (MAXMB, D/TN)
__global__ __launch_bounds__(256, 2) void ffn2_kernel(
    const unsigned short* __restrict__ H, const unsigned short* __restrict__ W2t,
    const float* __restrict__ b2,
    const int* __restrict__ mb_e, const int* __restrict__ mb_m0,
    unsigned short* __restrict__ Y) {
    int e = mb_e[blockIdx.x];
    if (e < 0) return;
    int m0 = mb_m0[blockIdx.x];
    int n0 = blockIdx.y * TN;
    const unsigned short* Bw = W2t + (size_t)e * D_ * F_;

    __shared__ __align__(16) unsigned short lA[TM*BK];
    __shared__ __align__(16) unsigned short lB[TN*BK];

    int t = threadIdx.x;
    int lane = t & 63;
    int wv = t >> 6;
    int wrow = (wv >> 1) * 64, wcol = (wv & 1) * 128;
    int lr = lane & 15, q = lane >> 4;

    int ar0 = t >> 2;
    int ac  = (t & 3) * 8;
    const unsigned short* pa0 = H + (size_t)(m0 + ar0)      * F_ + ac;
    const unsigned short* pa1 = H + (size_t)(m0 + 64 + ar0) * F_ + ac;
    const unsigned short* pb0 = Bw + (size_t)(n0 + ar0)       * F_ + ac;
    const unsigned short* pb1 = Bw + (size_t)(n0 + 64  + ar0) * F_ + ac;
    const unsigned short* pb2 = Bw + (size_t)(n0 + 128 + ar0) * F_ + ac;
    const unsigned short* pb3 = Bw + (size_t)(n0 + 192 + ar0) * F_ + ac;

    f32x4 acc[4][8];
    #pragma unroll
    for (int mi = 0; mi < 4; ++mi)
        #pragma unroll
        for (int ni = 0; ni < 8; ++ni)
            acc[mi][ni] = (f32x4){0.f, 0.f, 0.f, 0.f};

    for (int kk = 0; kk < F_/BK; ++kk) {
        int k0 = kk * BK;
        gl_lds16(pa0 + k0, &lA[t*8]);
        gl_lds16(pa1 + k0, &lA[2048 + t*8]);
        gl_lds16(pb0 + k0, &lB[t*8]);
        gl_lds16(pb1 + k0, &lB[2048 + t*8]);
        gl_lds16(pb2 + k0, &lB[4096 + t*8]);
        gl_lds16(pb3 + k0, &lB[6144 + t*8]);
        asm volatile("s_waitcnt vmcnt(0)" ::: "memory");
        __syncthreads();
        short8 af[4], bf[8];
        #pragma unroll
        for (int mi = 0; mi < 4; ++mi)
            af[mi] = *(const short8*)&lA[(wrow + mi*16 + lr)*BK + q*8];
        #pragma unroll
        for (int ni = 0; ni < 8; ++ni)
            bf[ni] = *(const short8*)&lB[(wcol + ni*16 + lr)*BK + q*8];
        #pragma unroll
        for (int mi = 0; mi < 4; ++mi)
            #pragma unroll
            for (int ni = 0; ni < 8; ++ni)
                acc[mi][ni] = __builtin_amdgcn_mfma_f32_16x16x32_bf16(
                    af[mi], bf[ni], acc[mi][ni], 0, 0, 0);
        __syncthreads();
    }

    const float* b2e = b2 + (size_t)e * D_;
    #pragma unroll
    for (int mi = 0; mi < 4; ++mi) {
        int gr = m0 + wrow + mi*16 + q*4;
        #pragma unroll
        for (int ni = 0; ni < 8; ++ni) {
            int dcol = n0 + wcol + ni*16 + lr;
            float bb = b2e[dcol];
            #pragma unroll
            for (int r = 0; r < 4; ++r)
                Y[(size_t)(gr + r) * D_ + dcol] = f2b(acc[mi][ni][r] + bb);
        }
    }
}

// ---------------- combine: out[t] = w0*Y[s0] + w1*Y[s1] ----------------
// one block per token (256 threads x 4 floats = D)
__global__ __launch_bounds__(256) void combine_kernel(
    const unsigned short* __restrict__ Y, const int* __restrict__ slots,
    const float* __restrict__ topw, float* __restrict__ out) {
    int t  = blockIdx.x;
    int d4 = threadIdx.x * 4;
    int s0 = slots[t*2], s1 = slots[t*2+1];
    float w0 = topw[t*2], w1 = topw[t*2+1];
    ushort4 y0 = *(const ushort4*)&Y[(size_t)s0 * D_ + d4];
    ushort4 y1 = *(const ushort4*)&Y[(size_t)s1 * D_ + d4];
    float4 o;
    o.x = w0*b2f(y0.x) + w1*b2f(y1.x);
    o.y = w0*b2f(y0.y) + w1*b2f(y1.y);
    o.z = w0*b2f(y0.z) + w1*b2f(y1.z);
    o.w = w0*b2f(y0.w) + w1*b2f(y1.w);
    *(float4*)&out[(size_t)t * D_ + d4] = o;
}

extern "C" void kernel_launch(void* const* d_in, const int* in_sizes, int n_in,
                              void* d_out, int out_size, void* d_ws, size_t ws_size,
                              hipStream_t stream) {
    const float* x  = (const float*)d_in[0];
    const float* Wg = (const float*)d_in[1];
    const float* bg = (const float*)d_in[2];
    const float* W1 = (const float*)d_in[3];
    const float* b1 = (const float*)d_in[4];
    const float* W2 = (const float*)d_in[5];
    const float* b2 = (const float*)d_in[6];
    float* out = (float*)d_out;

    char* wsp = (char*)d_ws;
    size_t off = 0;
    auto alloc = [&](size_t bytes) {
        void* p = wsp + off;
        off += (bytes + 255) & ~(size_t)255;
        return p;
    };
    int*   topi    = (int*)  alloc((size_t)NR_*4);
    float* topw    = (float*)alloc((size_t)NR_*4);
    int*   slots   = (int*)  alloc((size_t)NR_*4);
    int*   counts  = (int*)  alloc(E_*4);
    int*   offs    = (int*)  alloc((E_+1)*4);
    int*   cursors = (int*)  alloc(E_*4);
    int*   mb_e    = (int*)  alloc(MAXMB*4);
    int*   mb_m0   = (int*)  alloc(MAXMB*4);
    int*   perm    = (int*)  alloc((size_t)MAXP*4);
    unsigned short* Xb  = (unsigned short*)alloc((size_t)N_*D_*2);
    unsigned short* W1t = (unsigned short*)alloc((size_t)E_*D_*F_*2);
    unsigned short* W2t = (unsigned short*)alloc((size_t)E_*D_*F_*2);
    unsigned short* Hb  = (unsigned short*)alloc((size_t)MAXP*F_*2);
    unsigned short* Yb  = (unsigned short*)alloc((size_t)MAXP*D_*2);

    hipMemsetAsync(counts, 0, E_*4, stream);
    hipMemsetAsync(perm, 0, (size_t)MAXP*4, stream);

    gate_kernel<<<N_/4, 256, 0, stream>>>(x, Wg, bg, topi, topw, counts);
    scan_kernel<<<1, 64, 0, stream>>>(counts, offs, cursors, mb_e, mb_m0);
    scatter_kernel<<<N_/256, 256, 0, stream>>>(topi, cursors, perm, slots);
    castx_kernel<<<(N_*(size_t)D_/4)/256, 256, 0, stream>>>(x, Xb);
    tcast_kernel<<<dim3(D_/64, F_/64, E_), 256, 0, stream>>>(W1, W1t, D_, F_);
    tcast_kernel<<<dim3(F_/64, D_/64, E_), 256, 0, stream>>>(W2, W2t, F_, D_);
    ffn1_kernel<<<dim3(MAXMB, F_/TN), 256, 0, stream>>>(Xb, W1t, b1, perm, mb_e, mb_m0, Hb);
    ffn2_kernel<<<dim3(MAXMB, D_/TN), 256, 0, stream>>>(Hb, W2t, b2, mb_e, mb_m0, Yb);
    combine_kernel<<<N_, 256, 0, stream>>>(Yb, slots, topw, out);
}

// Round 4
// 1086.762 us; speedup vs baseline: 1.2851x; 1.0455x over previous
//
#include <hip/hip_runtime.h>
#include <cstdint>

#define B_ 4
#define T_ 2048
#define D_ 1024
#define E_ 8
#define F_ 4096
#define K_ 2
#define N_ (B_*T_)      // 8192 tokens
#define NR_ (N_*K_)     // 16384 routed slots

#define TM 128
#define BK 64
#define MAXP (NR_ + E_*TM)       // padded slot capacity (17408)
#define MAXMB (NR_/TM + E_)      // max M-blocks (136)

typedef __attribute__((ext_vector_type(8))) short short8;
typedef __attribute__((ext_vector_type(4))) float f32x4;

typedef const __attribute__((address_space(1))) unsigned int* gp1_t;
typedef __attribute__((address_space(3))) unsigned int* lp3_t;

__device__ __forceinline__ void gl_lds16(const void* g, void* l) {
    __builtin_amdgcn_global_load_lds((gp1_t)g, (lp3_t)l, 16, 0, 0);
}

__device__ __forceinline__ unsigned short f2b(float f) {
    union { float f; unsigned int u; } v; v.f = f;
    unsigned int u = v.u;
    return (unsigned short)((u + 0x7FFFu + ((u >> 16) & 1u)) >> 16);
}

__device__ __forceinline__ float b2f(unsigned short u) {
    union { unsigned int i; float f; } v; v.i = ((unsigned int)u) << 16;
    return v.f;
}

__device__ __forceinline__ float gelu_exact(float x) {
    return 0.5f * x * (1.0f + erff(x * 0.70710678118654752440f));
}

// ---------------- gate: fp32 logits, top-2, softmax ----------------
__global__ __launch_bounds__(256) void gate_kernel(
    const float* __restrict__ x, const float* __restrict__ Wg,
    const float* __restrict__ bg, int* __restrict__ topi,
    float* __restrict__ topw, int* __restrict__ counts) {
    int tid  = threadIdx.x;
    int lane = tid & 63;
    int tok  = blockIdx.x * 4 + (tid >> 6);
    int e = lane & 7;
    int c = lane >> 3;
    const float4* xp = (const float4*)(x + (size_t)tok * D_ + c * 128);
    const float*  wp = Wg + (size_t)(c * 128) * E_ + e;
    float acc = 0.f;
    #pragma unroll 8
    for (int i = 0; i < 32; ++i) {
        float4 xv = xp[i];
        acc += xv.x * wp[(i*4+0)*E_];
        acc += xv.y * wp[(i*4+1)*E_];
        acc += xv.z * wp[(i*4+2)*E_];
        acc += xv.w * wp[(i*4+3)*E_];
    }
    acc += __shfl_xor(acc, 8, 64);
    acc += __shfl_xor(acc, 16, 64);
    acc += __shfl_xor(acc, 32, 64);
    float logit = acc + bg[e];
    float v1 = -3.4e38f, v2 = -3.4e38f; int i1 = -1, i2 = -1;
    for (int ee = 0; ee < 8; ++ee) {
        float le = __shfl(logit, ee, 64);
        if (le > v1) { v2 = v1; i2 = i1; v1 = le; i1 = ee; }
        else if (le > v2) { v2 = le; i2 = ee; }
    }
    if (lane == 0) {
        float p2 = expf(v2 - v1);
        float s  = 1.0f + p2;
        topi[tok*2]   = i1; topw[tok*2]   = 1.0f / s;
        topi[tok*2+1] = i2; topw[tok*2+1] = p2 / s;
        atomicAdd(&counts[i1], 1);
        atomicAdd(&counts[i2], 1);
    }
}

// scan: padded offsets + flat M-block tables
__global__ void scan_kernel(const int* __restrict__ counts,
                            int* __restrict__ offs, int* __restrict__ cursors,
                            int* __restrict__ mb_e, int* __restrict__ mb_m0) {
    if (threadIdx.x == 0) {
        int s = 0, mb = 0;
        for (int e = 0; e < E_; ++e) {
            offs[e] = s; cursors[e] = s;
            int nb = (counts[e] + TM - 1) / TM;
            for (int i = 0; i < nb; ++i) { mb_e[mb] = e; mb_m0[mb] = s + i*TM; ++mb; }
            s += nb * TM;
        }
        offs[E_] = s;
        for (int b = mb; b < MAXMB; ++b) mb_e[b] = -1;
    }
}

__global__ __launch_bounds__(256) void scatter_kernel(
    const int* __restrict__ topi, int* __restrict__ cursors,
    int* __restrict__ perm, int* __restrict__ slots) {
    int t = blockIdx.x * blockDim.x + threadIdx.x;
    if (t >= N_) return;
    #pragma unroll
    for (int k = 0; k < K_; ++k) {
        int e = topi[t*2 + k];
        int pos = atomicAdd(&cursors[e], 1);
        perm[pos] = t;
        slots[t*2 + k] = pos;
    }
}

// ---------------- casts ----------------
__global__ __launch_bounds__(256) void castx_kernel(
    const float* __restrict__ x, unsigned short* __restrict__ xb) {
    int i = blockIdx.x * blockDim.x + threadIdx.x;   // over N*D/4
    float4 v = ((const float4*)x)[i];
    ushort4 o; o.x = f2b(v.x); o.y = f2b(v.y); o.z = f2b(v.z); o.w = f2b(v.w);
    ((ushort4*)xb)[i] = o;
}

// batched fp32 [R,C] -> bf16 [C,R]; 64x64 tile, vectorized
__global__ __launch_bounds__(256) void tcast_kernel(
    const float* __restrict__ src, unsigned short* __restrict__ dst, int R, int C) {
    __shared__ float tile[64][65];
    int rb = blockIdx.x * 64, cb = blockIdx.y * 64;
    const float* s = src + (size_t)blockIdx.z * R * C;
    unsigned short* d = dst + (size_t)blockIdx.z * R * C;
    int tx = threadIdx.x & 15, ty = threadIdx.x >> 4;   // 16 x 16
    #pragma unroll
    for (int i = 0; i < 4; ++i) {
        int r = ty + i*16;
        float4 v = *(const float4*)&s[(size_t)(rb + r) * C + cb + tx*4];
        tile[r][tx*4+0] = v.x; tile[r][tx*4+1] = v.y;
        tile[r][tx*4+2] = v.z; tile[r][tx*4+3] = v.w;
    }
    __syncthreads();
    #pragma unroll
    for (int i = 0; i < 4; ++i) {
        int c = ty + i*16;                               // dst row
        ushort4 o;
        o.x = f2b(tile[tx*4+0][c]);
        o.y = f2b(tile[tx*4+1][c]);
        o.z = f2b(tile[tx*4+2][c]);
        o.w = f2b(tile[tx*4+3][c]);
        *(ushort4*)&d[(size_t)(cb + c) * R + rb + tx*4] = o;
    }
}

// ---------------- GEMM1: H = gelu(Xb[perm] @ W1[e] + b1[e]) ----------------
// 128x128 tile, BK=64; grid (MAXMB, F/128); acc 4x4, 4 waves/SIMD
__global__ __launch_bounds__(256, 4) void ffn1_kernel(
    const unsigned short* __restrict__ Xb, const unsigned short* __restrict__ W1t,
    const float* __restrict__ b1, const int* __restrict__ perm,
    const int* __restrict__ mb_e, const int* __restrict__ mb_m0,
    unsigned short* __restrict__ H) {
    int e = mb_e[blockIdx.x];
    if (e < 0) return;
    int m0 = mb_m0[blockIdx.x];
    int n0 = blockIdx.y * 128;
    const unsigned short* Bw = W1t + (size_t)e * F_ * D_;

    __shared__ __align__(16) unsigned short lA[128*BK];   // 16 KB
    __shared__ __align__(16) unsigned short lB[128*BK];   // 16 KB

    int t = threadIdx.x;
    int lane = t & 63;
    int wv = t >> 6;
    int wrow = (wv >> 1) * 64, wcol = (wv & 1) * 64;
    int lr = lane & 15, q = lane >> 4;

    int sr = t >> 3;          // staging row 0..31 per pass
    int sc = (t & 7) * 8;     // 16B chunk offset (ushorts)
    const unsigned short* pa[4];
    const unsigned short* pb[4];
    #pragma unroll
    for (int i = 0; i < 4; ++i) {
        int tok = perm[m0 + sr + 32*i];
        pa[i] = Xb + (size_t)tok * D_ + sc;
        pb[i] = Bw + (size_t)(n0 + sr + 32*i) * D_ + sc;
    }

    f32x4 acc[4][4];
    #pragma unroll
    for (int mi = 0; mi < 4; ++mi)
        #pragma unroll
        for (int ni = 0; ni < 4; ++ni)
            acc[mi][ni] = (f32x4){0.f, 0.f, 0.f, 0.f};

    for (int kk = 0; kk < D_/BK; ++kk) {
        int k0 = kk * BK;
        #pragma unroll
        for (int i = 0; i < 4; ++i) {
            gl_lds16(pa[i] + k0, &lA[i*2048 + t*8]);
            gl_lds16(pb[i] + k0, &lB[i*2048 + t*8]);
        }
        asm volatile("s_waitcnt vmcnt(0)" ::: "memory");
        __syncthreads();
        #pragma unroll
        for (int s = 0; s < 2; ++s) {
            short8 af[4], bf[4];
            #pragma unroll
            for (int mi = 0; mi < 4; ++mi)
                af[mi] = *(const short8*)&lA[(wrow + mi*16 + lr)*BK + s*32 + q*8];
            #pragma unroll
            for (int ni = 0; ni < 4; ++ni)
                bf[ni] = *(const short8*)&lB[(wcol + ni*16 + lr)*BK + s*32 + q*8];
            #pragma unroll
            for (int mi = 0; mi < 4; ++mi)
                #pragma unroll
                for (int ni = 0; ni < 4; ++ni)
                    acc[mi][ni] = __builtin_amdgcn_mfma_f32_16x16x32_bf16(
                        af[mi], bf[ni], acc[mi][ni], 0, 0, 0);
        }
        __syncthreads();
    }

    const float* b1e = b1 + (size_t)e * F_;
    #pragma unroll
    for (int mi = 0; mi < 4; ++mi) {
        int gr = m0 + wrow + mi*16 + q*4;
        #pragma unroll
        for (int ni = 0; ni < 4; ++ni) {
            int f = n0 + wcol + ni*16 + lr;
            float bb = b1e[f];
            #pragma unroll
            for (int r = 0; r < 4; ++r) {
                float h = gelu_exact(acc[mi][ni][r] + bb);
                H[(size_t)(gr + r) * F_ + f] = f2b(h);
            }
        }
    }
}

// ---------------- GEMM2: Y[p] = H[p] @ W2[e] + b2[e] (bf16 stores) ---------
// 128x256 tile, BK=64; grid (MAXMB, D/256); acc 4x8
__global__ __launch_bounds__(256, 2) void ffn2_kernel(
    const unsigned short* __restrict__ H, const unsigned short* __restrict__ W2t,
    const float* __restrict__ b2,
    const int* __restrict__ mb_e, const int* __restrict__ mb_m0,
    unsigned short* __restrict__ Y) {
    int e = mb_e[blockIdx.x];
    if (e < 0) return;
    int m0 = mb_m0[blockIdx.x];
    int n0 = blockIdx.y * 256;
    const unsigned short* Bw = W2t + (size_t)e * D_ * F_;

    __shared__ __align__(16) unsigned short lA[128*BK];   // 16 KB
    __shared__ __align__(16) unsigned short lB[256*BK];   // 32 KB

    int t = threadIdx.x;
    int lane = t & 63;
    int wv = t >> 6;
    int wrow = (wv >> 1) * 64, wcol = (wv & 1) * 128;
    int lr = lane & 15, q = lane >> 4;

    int sr = t >> 3;
    int sc = (t & 7) * 8;
    const unsigned short* pa[4];
    const unsigned short* pb[8];
    #pragma unroll
    for (int i = 0; i < 4; ++i)
        pa[i] = H + (size_t)(m0 + sr + 32*i) * F_ + sc;
    #pragma unroll
    for (int i = 0; i < 8; ++i)
        pb[i] = Bw + (size_t)(n0 + sr + 32*i) * F_ + sc;

    f32x4 acc[4][8];
    #pragma unroll
    for (int mi = 0; mi < 4; ++mi)
        #pragma unroll
        for (int ni = 0; ni < 8; ++ni)
            acc[mi][ni] = (f32x4){0.f, 0.f, 0.f, 0.f};

    for (int kk = 0; kk < F_/BK; ++kk) {
        int k0 = kk * BK;
        #pragma unroll
        for (int i = 0; i < 4; ++i)
            gl_lds16(pa[i] + k0, &lA[i*2048 + t*8]);
        #pragma unroll
        for (int i = 0; i < 8; ++i)
            gl_lds16(pb[i] + k0, &lB[i*2048 + t*8]);
        asm volatile("s_waitcnt vmcnt(0)" ::: "memory");
        __syncthreads();
        #pragma unroll
        for (int s = 0; s < 2; ++s) {
            short8 af[4], bf[8];
            #pragma unroll
            for (int mi = 0; mi < 4; ++mi)
                af[mi] = *(const short8*)&lA[(wrow + mi*16 + lr)*BK + s*32 + q*8];
            #pragma unroll
            for (int ni = 0; ni < 8; ++ni)
                bf[ni] = *(const short8*)&lB[(wcol + ni*16 + lr)*BK + s*32 + q*8];
            #pragma unroll
            for (int mi = 0; mi < 4; ++mi)
                #pragma unroll
                for (int ni = 0; ni < 8; ++ni)
                    acc[mi][ni] = __builtin_amdgcn_mfma_f32_16x16x32_bf16(
                        af[mi], bf[ni], acc[mi][ni], 0, 0, 0);
        }
        __syncthreads();
    }

    const float* b2e = b2 + (size_t)e * D_;
    #pragma unroll
    for (int mi = 0; mi < 4; ++mi) {
        int gr = m0 + wrow + mi*16 + q*4;
        #pragma unroll
        for (int ni = 0; ni < 8; ++ni) {
            int dcol = n0 + wcol + ni*16 + lr;
            float bb = b2e[dcol];
            #pragma unroll
            for (int r = 0; r < 4; ++r)
                Y[(size_t)(gr + r) * D_ + dcol] = f2b(acc[mi][ni][r] + bb);
        }
    }
}

// ---------------- combine: out[t] = w0*Y[s0] + w1*Y[s1] ----------------
__global__ __launch_bounds__(256) void combine_kernel(
    const unsigned short* __restrict__ Y, const int* __restrict__ slots,
    const float* __restrict__ topw, float* __restrict__ out) {
    int t  = blockIdx.x;
    int d4 = threadIdx.x * 4;
    int s0 = slots[t*2], s1 = slots[t*2+1];
    float w0 = topw[t*2], w1 = topw[t*2+1];
    ushort4 y0 = *(const ushort4*)&Y[(size_t)s0 * D_ + d4];
    ushort4 y1 = *(const ushort4*)&Y[(size_t)s1 * D_ + d4];
    float4 o;
    o.x = w0*b2f(y0.x) + w1*b2f(y1.x);
    o.y = w0*b2f(y0.y) + w1*b2f(y1.y);
    o.z = w0*b2f(y0.z) + w1*b2f(y1.z);
    o.w = w0*b2f(y0.w) + w1*b2f(y1.w);
    *(float4*)&out[(size_t)t * D_ + d4] = o;
}

extern "C" void kernel_launch(void* const* d_in, const int* in_sizes, int n_in,
                              void* d_out, int out_size, void* d_ws, size_t ws_size,
                              hipStream_t stream) {
    const float* x  = (const float*)d_in[0];
    const float* Wg = (const float*)d_in[1];
    const float* bg = (const float*)d_in[2];
    const float* W1 = (const float*)d_in[3];
    const float* b1 = (const float*)d_in[4];
    const float* W2 = (const float*)d_in[5];
    const float* b2 = (const float*)d_in[6];
    float* out = (float*)d_out;

    char* wsp = (char*)d_ws;
    size_t off = 0;
    auto alloc = [&](size_t bytes) {
        void* p = wsp + off;
        off += (bytes + 255) & ~(size_t)255;
        return p;
    };
    int*   topi    = (int*)  alloc((size_t)NR_*4);
    float* topw    = (float*)alloc((size_t)NR_*4);
    int*   slots   = (int*)  alloc((size_t)NR_*4);
    int*   counts  = (int*)  alloc(E_*4);
    int*   offs    = (int*)  alloc((E_+1)*4);
    int*   cursors = (int*)  alloc(E_*4);
    int*   mb_e    = (int*)  alloc(MAXMB*4);
    int*   mb_m0   = (int*)  alloc(MAXMB*4);
    int*   perm    = (int*)  alloc((size_t)MAXP*4);
    unsigned short* Xb  = (unsigned short*)alloc((size_t)N_*D_*2);
    unsigned short* W1t = (unsigned short*)alloc((size_t)E_*D_*F_*2);
    unsigned short* W2t = (unsigned short*)alloc((size_t)E_*D_*F_*2);
    unsigned short* Hb  = (unsigned short*)alloc((size_t)MAXP*F_*2);
    unsigned short* Yb  = (unsigned short*)alloc((size_t)MAXP*D_*2);

    hipMemsetAsync(counts, 0, E_*4, stream);
    hipMemsetAsync(perm, 0, (size_t)MAXP*4, stream);

    gate_kernel<<<N_/4, 256, 0, stream>>>(x, Wg, bg, topi, topw, counts);
    scan_kernel<<<1, 64, 0, stream>>>(counts, offs, cursors, mb_e, mb_m0);
    scatter_kernel<<<N_/256, 256, 0, stream>>>(topi, cursors, perm, slots);
    castx_kernel<<<(N_*(size_t)D_/4)/256, 256, 0, stream>>>(x, Xb);
    tcast_kernel<<<dim3(D_/64, F_/64, E_), 256, 0, stream>>>(W1, W1t, D_, F_);
    tcast_kernel<<<dim3(F_/64, D_/64, E_), 256, 0, stream>>>(W2, W2t, F_, D_);
    ffn1_kernel<<<dim3(MAXMB, F_/128), 256, 0, stream>>>(Xb, W1t, b1, perm, mb_e, mb_m0, Hb);
    ffn2_kernel<<<dim3(MAXMB, D_/256), 256, 0, stream>>>(Hb, W2t, b2, mb_e, mb_m0, Yb);
    combine_kernel<<<N_, 256, 0, stream>>>(Yb, slots, topw, out);
}